// Round 1
// baseline (82.119 us; speedup 1.0000x reference)
//
#include <hip/hip_runtime.h>

// Problem constants (fixed by the reference file)
#define BQ    64        // batches
#define NG    128       // nodes per batch
#define NE    65536     // input edges
#define TOPK  16
#define AUGE  (NE + BQ * TOPK)   // 66560 edges per row after augmentation
#define WORDS (NG * NG / 32)     // 512 words = 16384 bits = one batch's pair bitmap

// Structural insight (verified in prior rounds, absmax 0): LayerNorm over the
// size-1 last axis makes scores == beta (constant) for ANY inputs — the MLP is
// dead code. top_k therefore picks, per batch, the first TOPK row-major
// (sl,dl) pairs that are neither diagonal nor an existing same-batch edge
// (jax.lax.top_k tie-break: lowest flattened index).
//
// Round 6: single-launch, zero-workspace design. The old global 1 MiB exist
// map existed only to pass data from the scatter kernel to the select kernel.
// Per batch the exist set is 16384 bits = 2 KB — it fits in LDS. So block g
// owns batch g outright:
//   * streams the WHOLE edge list (512 KB; first block per XCD pulls it from
//     HBM, the other 7 hit L2 — 4 MB/XCD of reads vs 4 MB L2), setting bits
//     for batch-g edges in a private LDS bitmap,
//   * copies its own 1/64 slice of the edge list to the output in passing
//     (reuses the already-loaded registers),
//   * after one __syncthreads(), thread 0 scans the bitmap (diagonal bits
//     pre-set at init) and emits the first TOPK clear bits in ascending
//     flattened order.
// No second launch, no inter-kernel dependency, no global exist map, and no
// reliance on the harness's ws poison value (d_ws is now entirely unused).
__global__ __launch_bounds__(1024) void fused_kernel(
    const int4* __restrict__ src4, const int4* __restrict__ dst4,
    int* __restrict__ out)
{
    __shared__ unsigned bm[WORDS];   // bit idx = sl*128 + dl, 1 = excluded
    const int g = blockIdx.x;        // batch id, 0..63
    const int t = threadIdx.x;       // 0..1023

    // Init bitmap with the diagonal pre-marked (sl == dl excluded).
    // Word w covers idx [w*32, w*32+32): sl = w>>2, dl in [(w&3)*32, +32).
    if (t < WORDS) {
        int sl  = t >> 2;
        int dlo = (t & 3) << 5;
        unsigned m = (sl >= dlo && sl < dlo + 32) ? (1u << (sl - dlo)) : 0u;
        bm[t] = m;
    }
    __syncthreads();

    // Scan all 65536 edges (as 16384 int4 per row); 16 iterations x 1024 thr.
    // Slice ownership: block g copies int4 indices [g*256, g*256+256) == the
    // i with (i>>8)==g. Every edge in this problem is same-batch by
    // construction (dst = src//128*128 + r), so ~1024 bits get set per block;
    // the guard keeps us honest against the reference semantics anyway.
    #pragma unroll 4
    for (int c = 0; c < 16; ++c) {
        int i  = (c << 10) + t;          // int4 index 0..16383
        int4 s = src4[i];
        int4 d = dst4[i];
        if ((i >> 8) == g) {             // own slice: copy to output rows
            ((int4*)(out))[i]        = s;
            ((int4*)(out + AUGE))[i] = d;
        }
        #define TRY(SS, DD)                                                  \
            if (((SS) >> 7) == g && ((DD) >> 7) == g) {                      \
                int idx = (((SS) & 127) << 7) | ((DD) & 127);                \
                atomicOr(&bm[idx >> 5], 1u << (idx & 31));                   \
            }
        TRY(s.x, d.x) TRY(s.y, d.y) TRY(s.z, d.z) TRY(s.w, d.w)
        #undef TRY
    }
    __syncthreads();

    // Select: first TOPK clear bits in ascending idx (row-major tie-break of
    // jax.lax.top_k over a constant score field). Serial on thread 0 — the
    // answer is almost always inside word 0-1 (~6% bit density), and LDS
    // reads are a few cycles; worst case 512 words is still trivial.
    if (t == 0) {
        int found = 0;
        for (int w = 0; w < WORDS && found < TOPK; ++w) {
            unsigned inv = ~bm[w];       // 1 = free pair
            while (inv && found < TOPK) {
                int j = __ffs(inv) - 1;
                inv &= inv - 1;
                int idx = (w << 5) | j;
                out[NE   + (g << 4) + found]      = (g << 7) | (idx >> 7);  // src
                out[AUGE + NE + (g << 4) + found] = (g << 7) | (idx & 127); // dst
                ++found;
            }
        }
        if (g == 0) out[2 * AUGE] = BQ * TOPK;   // added_count = 1024
    }
}

extern "C" void kernel_launch(void* const* d_in, const int* in_sizes, int n_in,
                              void* d_out, int out_size, void* d_ws, size_t ws_size,
                              hipStream_t stream) {
    // Input order per setup_inputs():
    // 0:h 1:q 2:W1 3:b1 4:W2 5:b2 6:gamma 7:beta 8:edge_index 9:node_batch 10:top_k
    const int* edge_index = (const int*)d_in[8];
    const int4* e_src4 = (const int4*)edge_index;          // edge_index[0]
    const int4* e_dst4 = (const int4*)(edge_index + NE);   // edge_index[1]

    int* out = (int*)d_out;   // int32 output, 2*AUGE + 1 elements

    // d_ws intentionally unused: no workspace, no poison-value assumptions.
    (void)d_ws; (void)ws_size;

    fused_kernel<<<dim3(BQ), dim3(1024), 0, stream>>>(e_src4, e_dst4, out);
}